// Round 14
// baseline (180.177 us; speedup 1.0000x reference)
//
#include <hip/hip_runtime.h>
#include <hip/hip_bf16.h>

#define BS 512
#define LL 128
#define DD 512
#define KK 30
#define GG 8
#define EE 2048
#define HH 1024
#define NROWS (BS*KK)   // 15360
#define NG (BS/GG)      // 64

typedef __attribute__((ext_vector_type(8))) short bf16x8;
typedef __attribute__((ext_vector_type(4))) float f32x4;
typedef __attribute__((address_space(1))) const unsigned int gu32;
typedef __attribute__((address_space(3))) unsigned int lu32;

__device__ __forceinline__ unsigned short f2bf(float f){
  unsigned int x = __float_as_uint(f);
  x = (x + 0x7FFFu + ((x >> 16) & 1u)) >> 16;   // round-to-nearest-even
  return (unsigned short)x;
}
__device__ __forceinline__ float bf2f(unsigned short u){
  return __uint_as_float(((unsigned int)u) << 16);
}
__device__ __forceinline__ unsigned fkey(float f){   // monotonic float->uint
  unsigned b = __float_as_uint(f);
  return (b & 0x80000000u) ? ~b : (b | 0x80000000u);
}
__device__ __forceinline__ float fdec(unsigned k){
  unsigned b = (k & 0x80000000u) ? (k & 0x7FFFFFFFu) : ~k;
  return __uint_as_float(b);
}

#define FENCE asm volatile("" ::: "memory")
#define BARR  do{ FENCE; __builtin_amdgcn_s_barrier(); FENCE; }while(0)
#define LGK0  do{ asm volatile("s_waitcnt lgkmcnt(0)" ::: "memory"); \
                  __builtin_amdgcn_sched_barrier(0); }while(0)
#define VMW(n) asm volatile("s_waitcnt vmcnt(" #n ")" ::: "memory")

// ---------------------------------------------------------------------------
// Kernel 1 (fused): blocks [0,512): per-batch prep + gather -> nfeats, hval.
// Blocks [512,1024): w1 f32 -> w1t bf16 [N][K] transpose.
// Blocks [1024,1024+nw2): w2 f32 -> w2t bf16 [N][K] transpose (only when
// w2t has a dedicated region, i.e. does not overlay nfeats).
// ---------------------------------------------------------------------------
__global__ __launch_bounds__(256) void k_pg(const float* __restrict__ atten,
                                            const int* __restrict__ text,
                                            const float* __restrict__ features,
                                            const float* __restrict__ dlp_w,
                                            const float* __restrict__ dlp_b,
                                            const float* __restrict__ w1,
                                            unsigned short* __restrict__ w1t,
                                            const float* __restrict__ w2,
                                            unsigned short* __restrict__ w2t,
                                            unsigned short* __restrict__ nfeats,
                                            float* __restrict__ hval){
  __shared__ int sidx[KK];
  __shared__ float tile[32][33];

  if(blockIdx.x >= BS + 512){   // ---- w2 transpose+convert (sep path) ----
    const int blk = blockIdx.x - (BS + 512);  // 2048: 64 n-tiles x 32 k-tiles
    const int n0 = (blk & 63)*32, k0 = (blk >> 6)*32;
    const int r = threadIdx.x >> 3, c4 = (threadIdx.x & 7)*4;
    const float4 v = *(const float4*)(w2 + (size_t)(k0 + r)*EE + n0 + c4);
    tile[r][c4+0] = v.x; tile[r][c4+1] = v.y; tile[r][c4+2] = v.z; tile[r][c4+3] = v.w;
    __syncthreads();
    ushort4 u;
    u.x = f2bf(tile[c4+0][r]); u.y = f2bf(tile[c4+1][r]);
    u.z = f2bf(tile[c4+2][r]); u.w = f2bf(tile[c4+3][r]);
    *(ushort4*)(w2t + (size_t)(n0 + r)*HH + k0 + c4) = u;
    return;
  }
  if(blockIdx.x >= BS){   // ---- w1 transpose+convert ----
    const int blk = blockIdx.x - BS;          // 512: 32 n-tiles x 16 k-tiles
    const int n0 = (blk & 31)*32, k0 = (blk >> 5)*32;
    const int r = threadIdx.x >> 3, c4 = (threadIdx.x & 7)*4;
    const float4 v = *(const float4*)(w1 + (size_t)(k0 + r)*HH + n0 + c4);
    tile[r][c4+0] = v.x; tile[r][c4+1] = v.y; tile[r][c4+2] = v.z; tile[r][c4+3] = v.w;
    __syncthreads();
    ushort4 u;
    u.x = f2bf(tile[c4+0][r]); u.y = f2bf(tile[c4+1][r]);
    u.z = f2bf(tile[c4+2][r]); u.w = f2bf(tile[c4+3][r]);
    *(ushort4*)(w1t + (size_t)(n0 + r)*DD + k0 + c4) = u;
    return;
  }

  const int b = blockIdx.x;
  const int tid = threadIdx.x;
  const int wv = tid >> 6, lane = tid & 63;

  if(wv == 0){   // ---- prep on wave 0 (shuffle-only) ----
    const int t0 = text[b*LL + lane];
    const int t1 = text[b*LL + 64 + lane];
    int v, vi;
    if(t1 > t0){ v = t1; vi = lane + 64; } else { v = t0; vi = lane; }
#pragma unroll
    for(int off = 32; off; off >>= 1){
      const int ov = __shfl_xor(v, off), oi = __shfl_xor(vi, off);
      if(ov > v || (ov == v && oi < vi)){ v = ov; vi = oi; }
    }
    const int eos = vi;

    const float a0 = atten[(size_t)b*LL*LL + (size_t)eos*LL + lane];
    const float a1 = atten[(size_t)b*LL*LL + (size_t)eos*LL + 64 + lane];
    float r0 = (t0 == 0) ? 0.f : ((lane == 0 || lane == eos) ? -1.f : a0);
    float r1 = (t1 == 0) ? 0.f : ((lane + 64 == eos) ? -1.f : a1);
    for(int k = 0; k < KK; k++){
      float mv; int mi;
      if(r1 > r0){ mv = r1; mi = lane + 64; } else { mv = r0; mi = lane; }
#pragma unroll
      for(int off = 32; off; off >>= 1){
        const float ov = __shfl_xor(mv, off); const int oi = __shfl_xor(mi, off);
        if(ov > mv || (ov == mv && oi < mi)){ mv = ov; mi = oi; }
      }
      if(lane == 0) sidx[k] = mi;
      if(mi == lane)      r0 = -3.f;
      if(mi == lane + 64) r1 = -3.f;
    }
  }
  __syncthreads();

  for(int it = 0; it < 8; it++){
    const int r = it*4 + wv;
    if(r >= KK) break;
    const int l = sidx[r];
    const float4* fp = (const float4*)features + ((size_t)b*LL + l)*(DD/4);
    const float4 v0 = fp[lane], v1 = fp[64 + lane];
    float ss = v0.x*v0.x + v0.y*v0.y + v0.z*v0.z + v0.w*v0.w
             + v1.x*v1.x + v1.y*v1.y + v1.z*v1.z + v1.w*v1.w;
#pragma unroll
    for(int off = 32; off; off >>= 1) ss += __shfl_xor(ss, off);
    float hout = 0.f;
#pragma unroll
    for(int g = 0; g < GG; g++){
      const float4 w0 = ((const float4*)dlp_w)[g*(DD/4) + lane];
      const float4 w1v = ((const float4*)dlp_w)[g*(DD/4) + 64 + lane];
      float hg = v0.x*w0.x + v0.y*w0.y + v0.z*w0.z + v0.w*w0.w
               + v1.x*w1v.x + v1.y*w1v.y + v1.z*w1v.z + v1.w*w1v.w;
#pragma unroll
      for(int off = 32; off; off >>= 1) hg += __shfl_xor(hg, off);
      if(lane == g) hout = hg;
    }
    if(lane < GG) hval[(size_t)(b*KK + r)*GG + lane] = hout + dlp_b[lane];
    const float rn = 1.0f / (sqrtf(ss) + 1e-8f);
    ushort4 u0, u1;
    u0.x = f2bf(v0.x*rn); u0.y = f2bf(v0.y*rn); u0.z = f2bf(v0.z*rn); u0.w = f2bf(v0.w*rn);
    u1.x = f2bf(v1.x*rn); u1.y = f2bf(v1.y*rn); u1.z = f2bf(v1.z*rn); u1.w = f2bf(v1.w*rn);
    ushort4* np = (ushort4*)nfeats + (size_t)(b*KK + r)*(DD/4);
    np[lane] = u0; np[64 + lane] = u1;
  }
}

// ---------------------------------------------------------------------------
// Kernel 2 (merged): blocks [0,960): GEMM1 (128x128 tile, BK=64, 4 waves,
// 64KiB dbuf -> 2 blocks/CU, vmcnt(8), 2-tile lead, row-XOR swizzle, fused
// BN stats). Blocks [960,1984): grouped-expert linear -> nbbf + psq2.
// Both depend only on k_pg; dlp work fills CUs alongside g1. LDS unioned.
// ---------------------------------------------------------------------------
__global__ __launch_bounds__(256, 2) void k_dg1(const unsigned short* __restrict__ A,
                                                const unsigned short* __restrict__ Bt,
                                                const float* __restrict__ bias,
                                                unsigned short* __restrict__ obf,
                                                float* __restrict__ psum,
                                                float* __restrict__ psq,
                                                const float* __restrict__ hval,
                                                const float* __restrict__ dlp_lw,
                                                const float* __restrict__ dlp_lb,
                                                unsigned short* __restrict__ nbbf,
                                                float* __restrict__ psq2){
  __shared__ char smem[65536];
  const int tid = threadIdx.x;

  if(blockIdx.x >= 960){   // ================= dlp half =================
    float (*hs)[GG*KK] = (float(*)[GG*KK])smem;            // [8][240] f32
    float (*red)[4]    = (float(*)[4])(smem + GG*GG*KK*4); // [4][4]
    const int blk = blockIdx.x - 960;
    const int et = blk & 15;
    const int n  = blk >> 4;
    for(int i = tid; i < GG*GG*KK; i += 256){
      const int g = i / (GG*KK), tt = i % (GG*KK);
      const int m = tt / KK, kq = tt % KK;
      hs[g][tt] = hval[(size_t)(((n*GG + m)*KK) + kq)*GG + g];
    }
    __syncthreads();
    const int h = tid >> 7, c = tid & 127;
    const int e = et*128 + c;
    float acc[4] = {0.f, 0.f, 0.f, 0.f};
#pragma unroll 4
    for(int k = 0; k < GG*KK; k++){
      const float w = dlp_lw[(size_t)k*EE + e];
#pragma unroll
      for(int rr = 0; rr < 4; rr++) acc[rr] += hs[h*4 + rr][k] * w;
    }
    const float lb = dlp_lb[e];
    float sq[4];
#pragma unroll
    for(int rr = 0; rr < 4; rr++){
      const float v = acc[rr] + lb;
      nbbf[(size_t)(n*GG + h*4 + rr)*EE + e] = f2bf(v);
      sq[rr] = v*v;
    }
#pragma unroll
    for(int off = 32; off; off >>= 1)
#pragma unroll
      for(int rr = 0; rr < 4; rr++) sq[rr] += __shfl_xor(sq[rr], off);
    const int wv = tid >> 6, lane = tid & 63;
    if(lane == 0){
#pragma unroll
      for(int rr = 0; rr < 4; rr++) red[wv][rr] = sq[rr];
    }
    __syncthreads();
    if(tid < 8){
      const int hh = tid >> 2, rr = tid & 3;
      psq2[(size_t)(n*GG + hh*4 + rr)*16 + et] = red[hh*2][rr] + red[hh*2+1][rr];
    }
    return;
  }

  // ================= g1 half =================
  const int KD = DD, ND = HH, NBX = HH/128;      // 512, 1024, 8
  typedef short lds_t[2][128*64];
  lds_t* S = (lds_t*)smem;                       // [2][2][128*64] short = 64 KiB
  const int wave = tid >> 6, lane = tid & 63;
  const int wr = wave >> 1, wc = wave & 1;       // 2M x 2N waves
  const int lrow = lane & 15, kg = lane >> 4;

  const int cpx = 960 >> 3;                      // g1 subgrid = 960, % 8 == 0
  const int bid = (blockIdx.x & 7)*cpx + (blockIdx.x >> 3);
  const int bx = bid % NBX, by = bid / NBX;
  const int m0 = by*128, n0 = bx*128;

  const unsigned short* Ab = A  + (size_t)m0*KD;
  const unsigned short* Bb = Bt + (size_t)n0*KD;

#define G1STG(tt, p) { \
  _Pragma("unroll") \
  for(int c = 0; c < 4; c++){ \
    const int i_ = tid + c*256; const int r_ = i_ >> 3; \
    const int g_ = (i_ & 7) ^ (r_ & 7); \
    __builtin_amdgcn_global_load_lds((gu32*)(Ab + (size_t)r_*KD + (tt)*64 + g_*8), \
                                     (lu32*)(&S[p][0][i_*8]), 16, 0, 0); \
  } \
  _Pragma("unroll") \
  for(int c = 0; c < 4; c++){ \
    const int i_ = tid + c*256; const int r_ = i_ >> 3; \
    const int g_ = (i_ & 7) ^ (r_ & 7); \
    __builtin_amdgcn_global_load_lds((gu32*)(Bb + (size_t)r_*KD + (tt)*64 + g_*8), \
                                     (lu32*)(&S[p][1][i_*8]), 16, 0, 0); \
  } \
}

  f32x4 acc[4][4] = {};
  const int NT = KD/64;                          // 8
  G1STG(0, 0)
  G1STG(1, 1)

  const int arow = wr*64 + lrow;
  const int brow = wc*64 + lrow;
  const int gx0 = (kg       ^ (lrow & 7))*8;
  const int gx1 = ((4 + kg) ^ (lrow & 7))*8;

#pragma unroll 1
  for(int t = 0; t < NT; t++){
    const int p = t & 1;
    if(t < NT-1) VMW(8);
    else         VMW(0);
    BARR;
    const short* Abuf = &S[p][0][0];
    const short* Bbuf = &S[p][1][0];
    bf16x8 af[4], bg[4];
#pragma unroll
    for(int n = 0; n < 4; n++) bg[n] = *(const bf16x8*)(Bbuf + (brow + n*16)*64 + gx0);
#pragma unroll
    for(int m = 0; m < 4; m++) af[m] = *(const bf16x8*)(Abuf + (arow + m*16)*64 + gx0);
    __builtin_amdgcn_s_setprio(1);
#pragma unroll
    for(int m = 0; m < 4; m++)
#pragma unroll
      for(int n = 0; n < 4; n++)
        acc[m][n] = __builtin_amdgcn_mfma_f32_16x16x32_bf16(af[m], bg[n], acc[m][n], 0, 0, 0);
    __builtin_amdgcn_s_setprio(0);
#pragma unroll
    for(int n = 0; n < 4; n++) bg[n] = *(const bf16x8*)(Bbuf + (brow + n*16)*64 + gx1);
#pragma unroll
    for(int m = 0; m < 4; m++) af[m] = *(const bf16x8*)(Abuf + (arow + m*16)*64 + gx1);
    __builtin_amdgcn_s_setprio(1);
#pragma unroll
    for(int m = 0; m < 4; m++)
#pragma unroll
      for(int n = 0; n < 4; n++)
        acc[m][n] = __builtin_amdgcn_mfma_f32_16x16x32_bf16(af[m], bg[n], acc[m][n], 0, 0, 0);
    __builtin_amdgcn_s_setprio(0);
    BARR;
    if(t + 2 < NT){ G1STG(t+2, p) }
  }
#undef G1STG

  const int colb = n0 + wc*64 + lrow;
#pragma unroll
  for(int n = 0; n < 4; n++){
    const float bb = bias[colb + n*16];
    float sv = 0.f, qv = 0.f;
#pragma unroll
    for(int m = 0; m < 4; m++)
#pragma unroll
      for(int r = 0; r < 4; r++){
        const float v = acc[m][n][r] + bb; sv += v; qv += v*v;
      }
    sv += __shfl_xor(sv, 16); sv += __shfl_xor(sv, 32);
    qv += __shfl_xor(qv, 16); qv += __shfl_xor(qv, 32);
    if(lane < 16){
      psum[(size_t)(by*2 + wr)*ND + colb + n*16] = sv;
      psq [(size_t)(by*2 + wr)*ND + colb + n*16] = qv;
    }
#pragma unroll
    for(int m = 0; m < 4; m++){
      const int row = m0 + wr*64 + m*16 + kg*4;
#pragma unroll
      for(int r = 0; r < 4; r++)
        obf[(size_t)(row + r)*ND + colb + n*16] = f2bf(acc[m][n][r] + bb);
    }
  }
}

// ---------------------------------------------------------------------------
// Kernel 3 (fused): blocks [0,4): BN finalize. Blocks [4, 4+nw2): w2
// transpose (fallback path only, when w2t overlays nfeats).
// ---------------------------------------------------------------------------
__global__ __launch_bounds__(256) void k_bnw(const float* __restrict__ psum,
                                             const float* __restrict__ psq,
                                             const float* __restrict__ bn_g,
                                             const float* __restrict__ bn_b,
                                             float* __restrict__ sc,
                                             float* __restrict__ sh,
                                             const float* __restrict__ w2,
                                             unsigned short* __restrict__ w2t){
  if(blockIdx.x < 4){
    const int c = blockIdx.x*256 + threadIdx.x;
    float s = 0.f, q = 0.f;
    for(int i = 0; i < 240; i++){ s += psum[(size_t)i*HH + c]; q += psq[(size_t)i*HH + c]; }
    const float mu  = s * (1.0f/NROWS);
    const float var = q * (1.0f/NROWS) - mu*mu;
    const float sv  = bn_g[c] / sqrtf(var + 1e-5f);
    sc[c] = sv;
    sh[c] = bn_b[c] - mu*sv;
    return;
  }
  __shared__ float tile[32][33];
  const int blk = blockIdx.x - 4;
  const int n0 = (blk & 63)*32, k0 = (blk >> 6)*32;
  const int r = threadIdx.x >> 3, c4 = (threadIdx.x & 7)*4;
  const float4 v = *(const float4*)(w2 + (size_t)(k0 + r)*EE + n0 + c4);
  tile[r][c4+0] = v.x; tile[r][c4+1] = v.y; tile[r][c4+2] = v.z; tile[r][c4+3] = v.w;
  __syncthreads();
  ushort4 u;
  u.x = f2bf(tile[c4+0][r]); u.y = f2bf(tile[c4+1][r]);
  u.z = f2bf(tile[c4+2][r]); u.w = f2bf(tile[c4+3][r]);
  *(ushort4*)(w2t + (size_t)(n0 + r)*HH + k0 + c4) = u;
}

// ---------------------------------------------------------------------------
// Kernel 4: BN+ReLU in place on x1 (bf16) + pkey init.
// ---------------------------------------------------------------------------
__global__ __launch_bounds__(256) void k_bnrelu(unsigned short* __restrict__ x1,
                                                const float* __restrict__ sc,
                                                const float* __restrict__ sh,
                                                unsigned* __restrict__ pkey){
  const size_t i = (size_t)blockIdx.x*256 + threadIdx.x;   // chunk of 8 bf16
  const int c0 = (int)((i*8) & (HH-1));
  uint4 u = ((uint4*)x1)[i];
  unsigned short* us = (unsigned short*)&u;
  const float4 s0 = *(const float4*)(sc + c0), s1 = *(const float4*)(sc + c0 + 4);
  const float4 h0 = *(const float4*)(sh + c0), h1 = *(const float4*)(sh + c0 + 4);
  const float scv[8] = {s0.x,s0.y,s0.z,s0.w,s1.x,s1.y,s1.z,s1.w};
  const float shv[8] = {h0.x,h0.y,h0.z,h0.w,h1.x,h1.y,h1.z,h1.w};
#pragma unroll
  for(int j = 0; j < 8; j++)
    us[j] = f2bf(fmaxf(bf2f(us[j])*scv[j] + shv[j], 0.f));
  ((uint4*)x1)[i] = u;
  if(blockIdx.x < 1024)
    ((uint4*)pkey)[blockIdx.x*256 + threadIdx.x] =
        make_uint4(0x007FFFFFu, 0x007FFFFFu, 0x007FFFFFu, 0x007FFFFFu);  // key(-inf)
}

// ---------------------------------------------------------------------------
// Kernel 5 (GEMM2): R9-exact 256x256 tile, BK=64, 8 waves (2Mx4N), 128KiB
// dbuf, 8-phase counted-vmcnt schedule, 16x16x32 MFMA, row-XOR swizzle
// (measured ~0 conflicts). Pool epilogue lensk-free (all 30 rows valid).
// ---------------------------------------------------------------------------
__global__ __launch_bounds__(512, 2) void k_g2(const unsigned short* __restrict__ A,
                                               const unsigned short* __restrict__ Bt,
                                               unsigned* __restrict__ pkey){
  const int KD = HH, ND = EE, NBX = EE/256;      // 1024, 2048, 8
  __shared__ short S[2][2][256*64];              // 128 KiB
  const int tid  = threadIdx.x;
  const int wave = tid >> 6, lane = tid & 63;
  const int wr = wave >> 2, wc = wave & 3;       // 2M x 4N waves
  const int lrow = lane & 15, kg = lane >> 4;

  const int nwg = gridDim.x, cpx = nwg >> 3;
  const int bid = (blockIdx.x & 7)*cpx + (blockIdx.x >> 3);
  const int bx = bid % NBX, by = bid / NBX;
  const int m0 = by*256, n0 = bx*256;

  const unsigned short* Ab = A  + (size_t)m0*KD;
  const unsigned short* Bb = Bt + (size_t)n0*KD;

#define STG_A(tt, p, c) { \
  const int i_ = tid + (c)*512; const int r_ = i_ >> 3; \
  const int g_ = (i_ & 7) ^ (r_ & 7); \
  __builtin_amdgcn_global_load_lds((gu32*)(Ab + (size_t)r_*KD + (tt)*64 + g_*8), \
                                   (lu32*)(&S[p][0][i_*8]), 16, 0, 0); }
#define STG_B(tt, p, c) { \
  const int i_ = tid + (c)*512; const int r_ = i_ >> 3; \
  const int g_ = (i_ & 7) ^ (r_ & 7); \
  __builtin_amdgcn_global_load_lds((gu32*)(Bb + (size_t)r_*KD + (tt)*64 + g_*8), \
                                   (lu32*)(&S[p][1][i_*8]), 16, 0, 0); }
#define DSR_B(gx)  _Pragma("unroll") for(int n = 0; n < 4; n++) \
    bg[n] = *(const bf16x8*)(Bbuf + (brow + n*16)*64 + (gx));
#define DSR_AL(gx) _Pragma("unroll") for(int m = 0; m < 4; m++) \
    af[m] = *(const bf16x8*)(Abuf + (arow + m*16)*64 + (gx));
#define DSR_AH(gx) _Pragma("unroll") for(int m = 0; m < 4; m++) \
    af[m] = *(const bf16x8*)(Abuf + (arow + 64 + m*16)*64 + (gx));
#define MFMA_L do{ __builtin_amdgcn_s_setprio(1); \
  _Pragma("unroll") for(int m = 0; m < 4; m++) \
  _Pragma("unroll") for(int n = 0; n < 4; n++) \
    acc[m][n] = __builtin_amdgcn_mfma_f32_16x16x32_bf16(af[m], bg[n], acc[m][n], 0, 0, 0); \
  __builtin_amdgcn_s_setprio(0); }while(0)
#define MFMA_H do{ __builtin_amdgcn_s_setprio(1); \
  _Pragma("unroll") for(int m = 0; m < 4; m++) \
  _Pragma("unroll") for(int n = 0; n < 4; n++) \
    acc[4+m][n] = __builtin_amdgcn_mfma_f32_16x16x32_bf16(af[m], bg[n], acc[4+m][n], 0, 0, 0); \
  __builtin_amdgcn_s_setprio(0); }while(0)

  f32x4 acc[8][4] = {};
  const int NT = KD/64;

  const int arow = wr*128 + lrow;
  const int brow = wc*64  + lrow;
  const int gx0 = (kg       ^ (lrow & 7))*8;
  const int gx1 = ((4 + kg) ^ (lrow & 7))*8;

  STG_A(0, 0, 0) STG_A(0, 0, 2)
  STG_B(0, 0, 0) STG_B(0, 0, 1) STG_B(0, 0, 2) STG_B(0, 0, 3)
  STG_A(0, 0, 1) STG_A(0, 0, 3)
  VMW(2); BARR;

#pragma unroll 1
  for(int t = 0; t < NT-1; t++){
    const int p = t & 1, q = p ^ 1;
    const short* Abuf = &S[p][0][0];
    const short* Bbuf = &S[p][1][0];
    bf16x8 bg[4], af[4];
    DSR_B(gx0); DSR_AL(gx0);
    STG_A(t+1, q, 0) STG_A(t+1, q, 2)
    VMW(2);
    BARR; LGK0;
    MFMA_L;
    BARR;
    DSR_AH(gx0);
    STG_B(t+1, q, 0) STG_B(t+1, q, 1)
    BARR; LGK0;
    MFMA_H;
    BARR;
    DSR_B(gx1); DSR_AL(gx1);
    STG_B(t+1, q, 2) STG_B(t+1, q, 3)
    BARR; LGK0;
    MFMA_L;
    BARR;
    DSR_AH(gx1);
    STG_A(t+1, q, 1) STG_A(t+1, q, 3)
    VMW(2);
    BARR; LGK0;
    MFMA_H;
    BARR;
  }
  {
    const int p = (NT-1) & 1;
    const short* Abuf = &S[p][0][0];
    const short* Bbuf = &S[p][1][0];
    bf16x8 bg[4], af[4];
    DSR_B(gx0); DSR_AL(gx0);
    VMW(0);
    BARR; LGK0;
    MFMA_L;
    BARR;
    DSR_AH(gx0);
    BARR; LGK0;
    MFMA_H;
    BARR;
    DSR_B(gx1); DSR_AL(gx1);
    BARR; LGK0;
    MFMA_L;
    BARR;
    DSR_AH(gx1);
    LGK0;
    MFMA_H;
  }
#undef STG_A
#undef STG_B
#undef DSR_B
#undef DSR_AL
#undef DSR_AH
#undef MFMA_L
#undef MFMA_H

  // ---- two-level segmented max-pool: regs -> LDS (atomicMax) -> global ----
  __syncthreads();
  unsigned* pool = (unsigned*)&S[0][0][0];
  const int b0 = m0 / KK;
  const int b1 = (m0 + 255) / KK;
  const int nseg = b1 - b0 + 1;                  // <= 10
  for(int i = tid; i < nseg*256; i += 512) pool[i] = 0x007FFFFFu;   // fkey(-inf)
  __syncthreads();
  const int lcol = wc*64 + lrow;
  {
    int cur_b = -1;
    float mx[4];
#pragma unroll
    for(int m = 0; m < 8; m++){
#pragma unroll
      for(int r = 0; r < 4; r++){
        const int row = m0 + wr*128 + m*16 + kg*4 + r;
        const int bt = row / KK;
        if(bt != cur_b){
          if(cur_b >= 0){
#pragma unroll
            for(int n = 0; n < 4; n++)
              atomicMax(&pool[(cur_b - b0)*256 + lcol + n*16], fkey(mx[n]));
          }
          cur_b = bt;
#pragma unroll
          for(int n = 0; n < 4; n++) mx[n] = -INFINITY;
        }
#pragma unroll
        for(int n = 0; n < 4; n++) mx[n] = fmaxf(mx[n], acc[m][n][r]);
      }
    }
#pragma unroll
    for(int n = 0; n < 4; n++)
      atomicMax(&pool[(cur_b - b0)*256 + lcol + n*16], fkey(mx[n]));
  }
  __syncthreads();
  for(int e = tid; e < nseg*256; e += 512){
    const int seg = e >> 8, col = e & 255;
    atomicMax(&pkey[(size_t)(b0 + seg)*ND + n0 + col], pool[e]);
  }
}

// ---------------------------------------------------------------------------
// Kernel 6: finalize output — pooled + b2 + l2norm(nb) (rn from psq2).
// ---------------------------------------------------------------------------
__global__ __launch_bounds__(256) void k_final(const unsigned* __restrict__ pkey,
                                               const float* __restrict__ b2,
                                               const unsigned short* __restrict__ nbbf,
                                               const float* __restrict__ psq2,
                                               float* __restrict__ out){
  const size_t i = (size_t)blockIdx.x*256 + threadIdx.x;   // per 4 elems
  const int c0 = (int)((i*4) & (EE-1));
  const int b = (int)(blockIdx.x >> 1);                    // 2 blocks per row
  float ssq = 0.f;
#pragma unroll
  for(int j = 0; j < 16; j++) ssq += psq2[(size_t)b*16 + j];
  const float rn = 1.0f / (sqrtf(ssq) + 1e-8f);
  const uint4 k = ((const uint4*)pkey)[i];
  const ushort4 nb4 = ((const ushort4*)nbbf)[i];
  const float4 bb = *(const float4*)(b2 + c0);
  float4 o;
  o.x = fdec(k.x) + bb.x + bf2f(nb4.x)*rn;
  o.y = fdec(k.y) + bb.y + bf2f(nb4.y)*rn;
  o.z = fdec(k.z) + bb.z + bf2f(nb4.z)*rn;
  o.w = fdec(k.w) + bb.w + bf2f(nb4.w)*rn;
  ((float4*)out)[i] = o;
}

// ---------------------------------------------------------------------------
extern "C" void kernel_launch(void* const* d_in, const int* in_sizes, int n_in,
                              void* d_out, int out_size, void* d_ws, size_t ws_size,
                              hipStream_t stream){
  const float* features = (const float*)d_in[0];
  const float* atten    = (const float*)d_in[1];
  const int*   text     = (const int*)  d_in[2];
  const float* dlp_w    = (const float*)d_in[4];
  const float* dlp_b    = (const float*)d_in[5];
  const float* dlp_lw   = (const float*)d_in[6];
  const float* dlp_lb   = (const float*)d_in[7];
  const float* w1       = (const float*)d_in[8];
  const float* b1       = (const float*)d_in[9];
  const float* bn_g     = (const float*)d_in[10];
  const float* bn_b     = (const float*)d_in[11];
  const float* w2       = (const float*)d_in[12];
  const float* b2       = (const float*)d_in[13];
  float* out = (float*)d_out;

  // Workspace layout with lifetime aliasing:
  char* ws = (char*)d_ws;
  float*          psum   = (float*)(ws + 0);               //   983,040 (240x1024)
  float*          psq    = (float*)(ws + 983040);          //   983,040
  unsigned short* w1t    = (unsigned short*)(ws + 1966080);// 1,048,576
  float*          hval   = (float*)(ws + 3014656);         //   491,520
  unsigned*       pkey   = (unsigned*)(ws + 0);            // 4,194,304 (overlay, live from k_bnrelu on)
  float*          sc     = (float*)(ws + 4196352);         //     4,096
  float*          sh     = (float*)(ws + 4200448);         //     4,096
  float*          psq2   = (float*)(ws + 4204544);         //    32,768 (512x16)
  unsigned short* nfeats = (unsigned short*)(ws + 4237312);// 15,728,640
  unsigned short* x1     = (unsigned short*)(ws + 19965952);//31,457,280
  unsigned short* nbbf   = (unsigned short*)(ws + 51423232);// 2,097,152 -> 53,520,384

  // w2t: dedicated region if workspace is large enough (parallel path,
  // transpose runs inside k_pg); else overlay nfeats (sequential path,
  // transpose runs in k_bnw after k_dg1 finishes reading nfeats).
  const int sep = (ws_size >= (size_t)53520384 + 4194304) ? 1 : 0;
  unsigned short* w2t = sep ? (unsigned short*)(ws + 53520384)
                            : (unsigned short*)(ws + 4237312);

  k_pg<<<BS + 512 + (sep ? 2048 : 0), 256, 0, stream>>>(
      atten, text, features, dlp_w, dlp_b, w1, w1t, w2, w2t, nfeats, hval);
  k_dg1<<<960 + 1024, 256, 0, stream>>>(nfeats, w1t, b1, x1, psum, psq,
                                        hval, dlp_lw, dlp_lb, nbbf, psq2);
  k_bnw<<<sep ? 4 : (4 + 2048), 256, 0, stream>>>(psum, psq, bn_g, bn_b,
                                                  sc, sh, w2, w2t);
  k_bnrelu<<<(NROWS*HH/8)/256, 256, 0, stream>>>(x1, sc, sh, pkey);
  k_g2<<<(EE/256)*(NROWS/256), 512, 0, stream>>>(x1, w2t, pkey);
  k_final<<<(BS*EE/4)/256, 256, 0, stream>>>(pkey, b2, nbbf, psq2, out);
}

// Round 15
// 177.523 us; speedup vs baseline: 1.0149x; 1.0149x over previous
//
#include <hip/hip_runtime.h>
#include <hip/hip_bf16.h>

#define BS 512
#define LL 128
#define DD 512
#define KK 30
#define GG 8
#define EE 2048
#define HH 1024
#define NROWS (BS*KK)   // 15360
#define NG (BS/GG)      // 64

typedef __attribute__((ext_vector_type(8))) short bf16x8;
typedef __attribute__((ext_vector_type(4))) float f32x4;
typedef __attribute__((address_space(1))) const unsigned int gu32;
typedef __attribute__((address_space(3))) unsigned int lu32;

__device__ __forceinline__ unsigned short f2bf(float f){
  unsigned int x = __float_as_uint(f);
  x = (x + 0x7FFFu + ((x >> 16) & 1u)) >> 16;   // round-to-nearest-even
  return (unsigned short)x;
}
__device__ __forceinline__ float bf2f(unsigned short u){
  return __uint_as_float(((unsigned int)u) << 16);
}
__device__ __forceinline__ unsigned fkey(float f){   // monotonic float->uint
  unsigned b = __float_as_uint(f);
  return (b & 0x80000000u) ? ~b : (b | 0x80000000u);
}
__device__ __forceinline__ float fdec(unsigned k){
  unsigned b = (k & 0x80000000u) ? (k & 0x7FFFFFFFu) : ~k;
  return __uint_as_float(b);
}

#define FENCE asm volatile("" ::: "memory")
#define BARR  do{ FENCE; __builtin_amdgcn_s_barrier(); FENCE; }while(0)
#define LGK0  do{ asm volatile("s_waitcnt lgkmcnt(0)" ::: "memory"); \
                  __builtin_amdgcn_sched_barrier(0); }while(0)
#define VMW(n) asm volatile("s_waitcnt vmcnt(" #n ")" ::: "memory")

// ---------------------------------------------------------------------------
// Kernel 1 (fused): blocks [0,512): per-batch prep + gather -> nfeats, hval.
// Blocks [512,1024): w1[512,1024] f32 -> w1t[1024,512] bf16 transpose.
// ---------------------------------------------------------------------------
__global__ __launch_bounds__(256) void k_pg(const float* __restrict__ atten,
                                            const int* __restrict__ text,
                                            const float* __restrict__ features,
                                            const float* __restrict__ dlp_w,
                                            const float* __restrict__ dlp_b,
                                            const float* __restrict__ w1,
                                            unsigned short* __restrict__ w1t,
                                            unsigned short* __restrict__ nfeats,
                                            float* __restrict__ hval){
  __shared__ int sidx[KK];
  __shared__ float tile[32][33];

  if(blockIdx.x >= BS){   // ---- w1 transpose+convert half ----
    const int blk = blockIdx.x - BS;
    const int n0 = (blk & 31)*32, k0 = (blk >> 5)*32;
    const int r = threadIdx.x >> 3, c4 = (threadIdx.x & 7)*4;
    const float4 v = *(const float4*)(w1 + (size_t)(k0 + r)*HH + n0 + c4);
    tile[r][c4+0] = v.x; tile[r][c4+1] = v.y; tile[r][c4+2] = v.z; tile[r][c4+3] = v.w;
    __syncthreads();
    ushort4 u;
    u.x = f2bf(tile[c4+0][r]); u.y = f2bf(tile[c4+1][r]);
    u.z = f2bf(tile[c4+2][r]); u.w = f2bf(tile[c4+3][r]);
    *(ushort4*)(w1t + (size_t)(n0 + r)*DD + k0 + c4) = u;
    return;
  }

  const int b = blockIdx.x;
  const int tid = threadIdx.x;
  const int wv = tid >> 6, lane = tid & 63;

  if(wv == 0){   // ---- prep on wave 0 (shuffle-only) ----
    const int t0 = text[b*LL + lane];
    const int t1 = text[b*LL + 64 + lane];
    int v, vi;
    if(t1 > t0){ v = t1; vi = lane + 64; } else { v = t0; vi = lane; }
#pragma unroll
    for(int off = 32; off; off >>= 1){
      const int ov = __shfl_xor(v, off), oi = __shfl_xor(vi, off);
      if(ov > v || (ov == v && oi < vi)){ v = ov; vi = oi; }
    }
    const int eos = vi;

    const float a0 = atten[(size_t)b*LL*LL + (size_t)eos*LL + lane];
    const float a1 = atten[(size_t)b*LL*LL + (size_t)eos*LL + 64 + lane];
    float r0 = (t0 == 0) ? 0.f : ((lane == 0 || lane == eos) ? -1.f : a0);
    float r1 = (t1 == 0) ? 0.f : ((lane + 64 == eos) ? -1.f : a1);
    for(int k = 0; k < KK; k++){
      float mv; int mi;
      if(r1 > r0){ mv = r1; mi = lane + 64; } else { mv = r0; mi = lane; }
#pragma unroll
      for(int off = 32; off; off >>= 1){
        const float ov = __shfl_xor(mv, off); const int oi = __shfl_xor(mi, off);
        if(ov > mv || (ov == mv && oi < mi)){ mv = ov; mi = oi; }
      }
      if(lane == 0) sidx[k] = mi;
      if(mi == lane)      r0 = -3.f;
      if(mi == lane + 64) r1 = -3.f;
    }
  }
  __syncthreads();

  for(int it = 0; it < 8; it++){
    const int r = it*4 + wv;
    if(r >= KK) break;
    const int l = sidx[r];
    const float4* fp = (const float4*)features + ((size_t)b*LL + l)*(DD/4);
    const float4 v0 = fp[lane], v1 = fp[64 + lane];
    float ss = v0.x*v0.x + v0.y*v0.y + v0.z*v0.z + v0.w*v0.w
             + v1.x*v1.x + v1.y*v1.y + v1.z*v1.z + v1.w*v1.w;
#pragma unroll
    for(int off = 32; off; off >>= 1) ss += __shfl_xor(ss, off);
    float hout = 0.f;
#pragma unroll
    for(int g = 0; g < GG; g++){
      const float4 w0 = ((const float4*)dlp_w)[g*(DD/4) + lane];
      const float4 w1v = ((const float4*)dlp_w)[g*(DD/4) + 64 + lane];
      float hg = v0.x*w0.x + v0.y*w0.y + v0.z*w0.z + v0.w*w0.w
               + v1.x*w1v.x + v1.y*w1v.y + v1.z*w1v.z + v1.w*w1v.w;
#pragma unroll
      for(int off = 32; off; off >>= 1) hg += __shfl_xor(hg, off);
      if(lane == g) hout = hg;
    }
    if(lane < GG) hval[(size_t)(b*KK + r)*GG + lane] = hout + dlp_b[lane];
    const float rn = 1.0f / (sqrtf(ss) + 1e-8f);
    ushort4 u0, u1;
    u0.x = f2bf(v0.x*rn); u0.y = f2bf(v0.y*rn); u0.z = f2bf(v0.z*rn); u0.w = f2bf(v0.w*rn);
    u1.x = f2bf(v1.x*rn); u1.y = f2bf(v1.y*rn); u1.z = f2bf(v1.z*rn); u1.w = f2bf(v1.w*rn);
    ushort4* np = (ushort4*)nfeats + (size_t)(b*KK + r)*(DD/4);
    np[lane] = u0; np[64 + lane] = u1;
  }
}

// ---------------------------------------------------------------------------
// Kernel 2: grouped-expert linear -> nbbf (bf16, UN-normalized) + per-row
// sumsq partials psq2[512][16] (deterministic unique-writer reduction).
// ---------------------------------------------------------------------------
__global__ __launch_bounds__(256) void k_dlp(const float* __restrict__ hval,
                                             const float* __restrict__ dlp_lw,
                                             const float* __restrict__ dlp_lb,
                                             unsigned short* __restrict__ nbbf,
                                             float* __restrict__ psq2){
  const int et = blockIdx.x;
  const int n  = blockIdx.y;
  const int tid = threadIdx.x;
  __shared__ float hs[GG][GG*KK];
  __shared__ float red[4][4];
  for(int i = tid; i < GG*GG*KK; i += 256){
    const int g = i / (GG*KK), tt = i % (GG*KK);
    const int m = tt / KK, kq = tt % KK;
    hs[g][tt] = hval[(size_t)(((n*GG + m)*KK) + kq)*GG + g];
  }
  __syncthreads();
  const int h = tid >> 7, c = tid & 127;
  const int e = et*128 + c;
  float acc[4] = {0.f, 0.f, 0.f, 0.f};
#pragma unroll 4
  for(int k = 0; k < GG*KK; k++){
    const float w = dlp_lw[(size_t)k*EE + e];
#pragma unroll
    for(int rr = 0; rr < 4; rr++) acc[rr] += hs[h*4 + rr][k] * w;
  }
  const float lb = dlp_lb[e];
  float sq[4];
#pragma unroll
  for(int rr = 0; rr < 4; rr++){
    const float v = acc[rr] + lb;
    nbbf[(size_t)(n*GG + h*4 + rr)*EE + e] = f2bf(v);
    sq[rr] = v*v;
  }
#pragma unroll
  for(int off = 32; off; off >>= 1)
#pragma unroll
    for(int rr = 0; rr < 4; rr++) sq[rr] += __shfl_xor(sq[rr], off);
  const int wv = tid >> 6, lane = tid & 63;
  if(lane == 0){
#pragma unroll
    for(int rr = 0; rr < 4; rr++) red[wv][rr] = sq[rr];
  }
  __syncthreads();
  if(tid < 8){
    const int hh = tid >> 2, rr = tid & 3;
    psq2[(size_t)(n*GG + hh*4 + rr)*16 + et] = red[hh*2][rr] + red[hh*2+1][rr];
  }
}

// ---------------------------------------------------------------------------
// Kernel 3 (GEMM1): 128x128 tile, BK=64, 4 waves, 64KiB dbuf -> 2 blocks/CU,
// grid 960. vmcnt(8), 2-tile lead, row-XOR swizzle, fused BN stats.
// ---------------------------------------------------------------------------
__global__ __launch_bounds__(256, 2) void k_g1(const unsigned short* __restrict__ A,
                                               const unsigned short* __restrict__ Bt,
                                               const float* __restrict__ bias,
                                               unsigned short* __restrict__ obf,
                                               float* __restrict__ psum,
                                               float* __restrict__ psq){
  const int KD = DD, ND = HH, NBX = HH/128;      // 512, 1024, 8
  __shared__ short S[2][2][128*64];              // 64 KiB
  const int tid  = threadIdx.x;
  const int wave = tid >> 6, lane = tid & 63;
  const int wr = wave >> 1, wc = wave & 1;       // 2M x 2N waves
  const int lrow = lane & 15, kg = lane >> 4;

  const int nwg = gridDim.x, cpx = nwg >> 3;     // 960 % 8 == 0
  const int bid = (blockIdx.x & 7)*cpx + (blockIdx.x >> 3);
  const int bx = bid % NBX, by = bid / NBX;
  const int m0 = by*128, n0 = bx*128;

  const unsigned short* Ab = A  + (size_t)m0*KD;
  const unsigned short* Bb = Bt + (size_t)n0*KD;

#define G1STG(tt, p) { \
  _Pragma("unroll") \
  for(int c = 0; c < 4; c++){ \
    const int i_ = tid + c*256; const int r_ = i_ >> 3; \
    const int g_ = (i_ & 7) ^ (r_ & 7); \
    __builtin_amdgcn_global_load_lds((gu32*)(Ab + (size_t)r_*KD + (tt)*64 + g_*8), \
                                     (lu32*)(&S[p][0][i_*8]), 16, 0, 0); \
  } \
  _Pragma("unroll") \
  for(int c = 0; c < 4; c++){ \
    const int i_ = tid + c*256; const int r_ = i_ >> 3; \
    const int g_ = (i_ & 7) ^ (r_ & 7); \
    __builtin_amdgcn_global_load_lds((gu32*)(Bb + (size_t)r_*KD + (tt)*64 + g_*8), \
                                     (lu32*)(&S[p][1][i_*8]), 16, 0, 0); \
  } \
}

  f32x4 acc[4][4] = {};
  const int NT = KD/64;                          // 8
  G1STG(0, 0)
  G1STG(1, 1)

  const int arow = wr*64 + lrow;
  const int brow = wc*64 + lrow;
  const int gx0 = (kg       ^ (lrow & 7))*8;
  const int gx1 = ((4 + kg) ^ (lrow & 7))*8;

#pragma unroll 1
  for(int t = 0; t < NT; t++){
    const int p = t & 1;
    if(t < NT-1) VMW(8);
    else         VMW(0);
    BARR;
    const short* Abuf = &S[p][0][0];
    const short* Bbuf = &S[p][1][0];
    bf16x8 af[4], bg[4];
#pragma unroll
    for(int n = 0; n < 4; n++) bg[n] = *(const bf16x8*)(Bbuf + (brow + n*16)*64 + gx0);
#pragma unroll
    for(int m = 0; m < 4; m++) af[m] = *(const bf16x8*)(Abuf + (arow + m*16)*64 + gx0);
    __builtin_amdgcn_s_setprio(1);
#pragma unroll
    for(int m = 0; m < 4; m++)
#pragma unroll
      for(int n = 0; n < 4; n++)
        acc[m][n] = __builtin_amdgcn_mfma_f32_16x16x32_bf16(af[m], bg[n], acc[m][n], 0, 0, 0);
    __builtin_amdgcn_s_setprio(0);
#pragma unroll
    for(int n = 0; n < 4; n++) bg[n] = *(const bf16x8*)(Bbuf + (brow + n*16)*64 + gx1);
#pragma unroll
    for(int m = 0; m < 4; m++) af[m] = *(const bf16x8*)(Abuf + (arow + m*16)*64 + gx1);
    __builtin_amdgcn_s_setprio(1);
#pragma unroll
    for(int m = 0; m < 4; m++)
#pragma unroll
      for(int n = 0; n < 4; n++)
        acc[m][n] = __builtin_amdgcn_mfma_f32_16x16x32_bf16(af[m], bg[n], acc[m][n], 0, 0, 0);
    __builtin_amdgcn_s_setprio(0);
    BARR;
    if(t + 2 < NT){ G1STG(t+2, p) }
  }
#undef G1STG

  const int colb = n0 + wc*64 + lrow;
#pragma unroll
  for(int n = 0; n < 4; n++){
    const float bb = bias[colb + n*16];
    float sv = 0.f, qv = 0.f;
#pragma unroll
    for(int m = 0; m < 4; m++)
#pragma unroll
      for(int r = 0; r < 4; r++){
        const float v = acc[m][n][r] + bb; sv += v; qv += v*v;
      }
    sv += __shfl_xor(sv, 16); sv += __shfl_xor(sv, 32);
    qv += __shfl_xor(qv, 16); qv += __shfl_xor(qv, 32);
    if(lane < 16){
      psum[(size_t)(by*2 + wr)*ND + colb + n*16] = sv;
      psq [(size_t)(by*2 + wr)*ND + colb + n*16] = qv;
    }
#pragma unroll
    for(int m = 0; m < 4; m++){
      const int row = m0 + wr*64 + m*16 + kg*4;
#pragma unroll
      for(int r = 0; r < 4; r++)
        obf[(size_t)(row + r)*ND + colb + n*16] = f2bf(acc[m][n][r] + bb);
    }
  }
}

// ---------------------------------------------------------------------------
// Kernel 4 (fused): blocks [0,4): BN finalize. Blocks [4, 4+2048): w2
// transpose+convert f32 -> bf16 [N][K].
// ---------------------------------------------------------------------------
__global__ __launch_bounds__(256) void k_bnw(const float* __restrict__ psum,
                                             const float* __restrict__ psq,
                                             const float* __restrict__ bn_g,
                                             const float* __restrict__ bn_b,
                                             float* __restrict__ sc,
                                             float* __restrict__ sh,
                                             const float* __restrict__ w2,
                                             unsigned short* __restrict__ w2t){
  if(blockIdx.x < 4){
    const int c = blockIdx.x*256 + threadIdx.x;
    float s = 0.f, q = 0.f;
    for(int i = 0; i < 240; i++){ s += psum[(size_t)i*HH + c]; q += psq[(size_t)i*HH + c]; }
    const float mu  = s * (1.0f/NROWS);
    const float var = q * (1.0f/NROWS) - mu*mu;
    const float sv  = bn_g[c] / sqrtf(var + 1e-5f);
    sc[c] = sv;
    sh[c] = bn_b[c] - mu*sv;
    return;
  }
  __shared__ float tile[32][33];
  const int blk = blockIdx.x - 4;
  const int n0 = (blk & 63)*32, k0 = (blk >> 6)*32;
  const int r = threadIdx.x >> 3, c4 = (threadIdx.x & 7)*4;
  const float4 v = *(const float4*)(w2 + (size_t)(k0 + r)*EE + n0 + c4);
  tile[r][c4+0] = v.x; tile[r][c4+1] = v.y; tile[r][c4+2] = v.z; tile[r][c4+3] = v.w;
  __syncthreads();
  ushort4 u;
  u.x = f2bf(tile[c4+0][r]); u.y = f2bf(tile[c4+1][r]);
  u.z = f2bf(tile[c4+2][r]); u.w = f2bf(tile[c4+3][r]);
  *(ushort4*)(w2t + (size_t)(n0 + r)*HH + k0 + c4) = u;
}

// ---------------------------------------------------------------------------
// Kernel 5: BN+ReLU in place on x1 (bf16) + pkey init.
// ---------------------------------------------------------------------------
__global__ __launch_bounds__(256) void k_bnrelu(unsigned short* __restrict__ x1,
                                                const float* __restrict__ sc,
                                                const float* __restrict__ sh,
                                                unsigned* __restrict__ pkey){
  const size_t i = (size_t)blockIdx.x*256 + threadIdx.x;   // chunk of 8 bf16
  const int c0 = (int)((i*8) & (HH-1));
  uint4 u = ((uint4*)x1)[i];
  unsigned short* us = (unsigned short*)&u;
  const float4 s0 = *(const float4*)(sc + c0), s1 = *(const float4*)(sc + c0 + 4);
  const float4 h0 = *(const float4*)(sh + c0), h1 = *(const float4*)(sh + c0 + 4);
  const float scv[8] = {s0.x,s0.y,s0.z,s0.w,s1.x,s1.y,s1.z,s1.w};
  const float shv[8] = {h0.x,h0.y,h0.z,h0.w,h1.x,h1.y,h1.z,h1.w};
#pragma unroll
  for(int j = 0; j < 8; j++)
    us[j] = f2bf(fmaxf(bf2f(us[j])*scv[j] + shv[j], 0.f));
  ((uint4*)x1)[i] = u;
  if(blockIdx.x < 1024)
    ((uint4*)pkey)[blockIdx.x*256 + threadIdx.x] =
        make_uint4(0x007FFFFFu, 0x007FFFFFu, 0x007FFFFFu, 0x007FFFFFu);  // key(-inf)
}

// ---------------------------------------------------------------------------
// Kernel 6 (GEMM2): R9-exact 256x256 tile, BK=64, 8 waves (2Mx4N), 128KiB
// dbuf, 8-phase counted-vmcnt schedule, 16x16x32 MFMA, row-XOR swizzle
// (measured ~0 conflicts). Pool epilogue lensk-free (all 30 rows valid).
// ---------------------------------------------------------------------------
__global__ __launch_bounds__(512, 2) void k_g2(const unsigned short* __restrict__ A,
                                               const unsigned short* __restrict__ Bt,
                                               unsigned* __restrict__ pkey){
  const int KD = HH, ND = EE, NBX = EE/256;      // 1024, 2048, 8
  __shared__ short S[2][2][256*64];              // 128 KiB
  const int tid  = threadIdx.x;
  const int wave = tid >> 6, lane = tid & 63;
  const int wr = wave >> 2, wc = wave & 3;       // 2M x 4N waves
  const int lrow = lane & 15, kg = lane >> 4;

  const int nwg = gridDim.x, cpx = nwg >> 3;
  const int bid = (blockIdx.x & 7)*cpx + (blockIdx.x >> 3);
  const int bx = bid % NBX, by = bid / NBX;
  const int m0 = by*256, n0 = bx*256;

  const unsigned short* Ab = A  + (size_t)m0*KD;
  const unsigned short* Bb = Bt + (size_t)n0*KD;

#define STG_A(tt, p, c) { \
  const int i_ = tid + (c)*512; const int r_ = i_ >> 3; \
  const int g_ = (i_ & 7) ^ (r_ & 7); \
  __builtin_amdgcn_global_load_lds((gu32*)(Ab + (size_t)r_*KD + (tt)*64 + g_*8), \
                                   (lu32*)(&S[p][0][i_*8]), 16, 0, 0); }
#define STG_B(tt, p, c) { \
  const int i_ = tid + (c)*512; const int r_ = i_ >> 3; \
  const int g_ = (i_ & 7) ^ (r_ & 7); \
  __builtin_amdgcn_global_load_lds((gu32*)(Bb + (size_t)r_*KD + (tt)*64 + g_*8), \
                                   (lu32*)(&S[p][1][i_*8]), 16, 0, 0); }
#define DSR_B(gx)  _Pragma("unroll") for(int n = 0; n < 4; n++) \
    bg[n] = *(const bf16x8*)(Bbuf + (brow + n*16)*64 + (gx));
#define DSR_AL(gx) _Pragma("unroll") for(int m = 0; m < 4; m++) \
    af[m] = *(const bf16x8*)(Abuf + (arow + m*16)*64 + (gx));
#define DSR_AH(gx) _Pragma("unroll") for(int m = 0; m < 4; m++) \
    af[m] = *(const bf16x8*)(Abuf + (arow + 64 + m*16)*64 + (gx));
#define MFMA_L do{ __builtin_amdgcn_s_setprio(1); \
  _Pragma("unroll") for(int m = 0; m < 4; m++) \
  _Pragma("unroll") for(int n = 0; n < 4; n++) \
    acc[m][n] = __builtin_amdgcn_mfma_f32_16x16x32_bf16(af[m], bg[n], acc[m][n], 0, 0, 0); \
  __builtin_amdgcn_s_setprio(0); }while(0)
#define MFMA_H do{ __builtin_amdgcn_s_setprio(1); \
  _Pragma("unroll") for(int m = 0; m < 4; m++) \
  _Pragma("unroll") for(int n = 0; n < 4; n++) \
    acc[4+m][n] = __builtin_amdgcn_mfma_f32_16x16x32_bf16(af[m], bg[n], acc[4+m][n], 0, 0, 0); \
  __builtin_amdgcn_s_setprio(0); }while(0)

  f32x4 acc[8][4] = {};
  const int NT = KD/64;

  const int arow = wr*128 + lrow;
  const int brow = wc*64  + lrow;
  const int gx0 = (kg       ^ (lrow & 7))*8;
  const int gx1 = ((4 + kg) ^ (lrow & 7))*8;

  STG_A(0, 0, 0) STG_A(0, 0, 2)
  STG_B(0, 0, 0) STG_B(0, 0, 1) STG_B(0, 0, 2) STG_B(0, 0, 3)
  STG_A(0, 0, 1) STG_A(0, 0, 3)
  VMW(2); BARR;

#pragma unroll 1
  for(int t = 0; t < NT-1; t++){
    const int p = t & 1, q = p ^ 1;
    const short* Abuf = &S[p][0][0];
    const short* Bbuf = &S[p][1][0];
    bf16x8 bg[4], af[4];
    DSR_B(gx0); DSR_AL(gx0);
    STG_A(t+1, q, 0) STG_A(t+1, q, 2)
    VMW(2);
    BARR; LGK0;
    MFMA_L;
    BARR;
    DSR_AH(gx0);
    STG_B(t+1, q, 0) STG_B(t+1, q, 1)
    BARR; LGK0;
    MFMA_H;
    BARR;
    DSR_B(gx1); DSR_AL(gx1);
    STG_B(t+1, q, 2) STG_B(t+1, q, 3)
    BARR; LGK0;
    MFMA_L;
    BARR;
    DSR_AH(gx1);
    STG_A(t+1, q, 1) STG_A(t+1, q, 3)
    VMW(2);
    BARR; LGK0;
    MFMA_H;
    BARR;
  }
  {
    const int p = (NT-1) & 1;
    const short* Abuf = &S[p][0][0];
    const short* Bbuf = &S[p][1][0];
    bf16x8 bg[4], af[4];
    DSR_B(gx0); DSR_AL(gx0);
    VMW(0);
    BARR; LGK0;
    MFMA_L;
    BARR;
    DSR_AH(gx0);
    BARR; LGK0;
    MFMA_H;
    BARR;
    DSR_B(gx1); DSR_AL(gx1);
    BARR; LGK0;
    MFMA_L;
    BARR;
    DSR_AH(gx1);
    LGK0;
    MFMA_H;
  }
#undef STG_A
#undef STG_B
#undef DSR_B
#undef DSR_AL
#undef DSR_AH
#undef MFMA_L
#undef MFMA_H

  // ---- two-level segmented max-pool: regs -> LDS (atomicMax) -> global ----
  __syncthreads();
  unsigned* pool = (unsigned*)&S[0][0][0];
  const int b0 = m0 / KK;
  const int b1 = (m0 + 255) / KK;
  const int nseg = b1 - b0 + 1;                  // <= 10
  for(int i = tid; i < nseg*256; i += 512) pool[i] = 0x007FFFFFu;   // fkey(-inf)
  __syncthreads();
  const int lcol = wc*64 + lrow;
  {
    int cur_b = -1;
    float mx[4];
#pragma unroll
    for(int m = 0; m < 8; m++){
#pragma unroll
      for(int r = 0; r < 4; r++){
        const int row = m0 + wr*128 + m*16 + kg*4 + r;
        const int bt = row / KK;
        if(bt != cur_b){
          if(cur_b >= 0){
#pragma unroll
            for(int n = 0; n < 4; n++)
              atomicMax(&pool[(cur_b - b0)*256 + lcol + n*16], fkey(mx[n]));
          }
          cur_b = bt;
#pragma unroll
          for(int n = 0; n < 4; n++) mx[n] = -INFINITY;
        }
#pragma unroll
        for(int n = 0; n < 4; n++) mx[n] = fmaxf(mx[n], acc[m][n][r]);
      }
    }
#pragma unroll
    for(int n = 0; n < 4; n++)
      atomicMax(&pool[(cur_b - b0)*256 + lcol + n*16], fkey(mx[n]));
  }
  __syncthreads();
  for(int e = tid; e < nseg*256; e += 512){
    const int seg = e >> 8, col = e & 255;
    atomicMax(&pkey[(size_t)(b0 + seg)*ND + n0 + col], pool[e]);
  }
}

// ---------------------------------------------------------------------------
// Kernel 7: finalize output — pooled + b2 + l2norm(nb) (rn from psq2).
// ---------------------------------------------------------------------------
__global__ __launch_bounds__(256) void k_final(const unsigned* __restrict__ pkey,
                                               const float* __restrict__ b2,
                                               const unsigned short* __restrict__ nbbf,
                                               const float* __restrict__ psq2,
                                               float* __restrict__ out){
  const size_t i = (size_t)blockIdx.x*256 + threadIdx.x;   // per 4 elems
  const int c0 = (int)((i*4) & (EE-1));
  const int b = (int)(blockIdx.x >> 1);                    // 2 blocks per row
  float ssq = 0.f;
#pragma unroll
  for(int j = 0; j < 16; j++) ssq += psq2[(size_t)b*16 + j];
  const float rn = 1.0f / (sqrtf(ssq) + 1e-8f);
  const uint4 k = ((const uint4*)pkey)[i];
  const ushort4 nb4 = ((const ushort4*)nbbf)[i];
  const float4 bb = *(const float4*)(b2 + c0);
  float4 o;
  o.x = fdec(k.x) + bb.x + bf2f(nb4.x)*rn;
  o.y = fdec(k.y) + bb.y + bf2f(nb4.y)*rn;
  o.z = fdec(k.z) + bb.z + bf2f(nb4.z)*rn;
  o.w = fdec(k.w) + bb.w + bf2f(nb4.w)*rn;
  ((float4*)out)[i] = o;
}

// ---------------------------------------------------------------------------
extern "C" void kernel_launch(void* const* d_in, const int* in_sizes, int n_in,
                              void* d_out, int out_size, void* d_ws, size_t ws_size,
                              hipStream_t stream){
  const float* features = (const float*)d_in[0];
  const float* atten    = (const float*)d_in[1];
  const int*   text     = (const int*)  d_in[2];
  const float* dlp_w    = (const float*)d_in[4];
  const float* dlp_b    = (const float*)d_in[5];
  const float* dlp_lw   = (const float*)d_in[6];
  const float* dlp_lb   = (const float*)d_in[7];
  const float* w1       = (const float*)d_in[8];
  const float* b1       = (const float*)d_in[9];
  const float* bn_g     = (const float*)d_in[10];
  const float* bn_b     = (const float*)d_in[11];
  const float* w2       = (const float*)d_in[12];
  const float* b2       = (const float*)d_in[13];
  float* out = (float*)d_out;

  // Workspace layout with lifetime aliasing:
  char* ws = (char*)d_ws;
  float*          psum   = (float*)(ws + 0);               //   983,040 (240x1024)
  float*          psq    = (float*)(ws + 983040);          //   983,040
  unsigned short* w1t    = (unsigned short*)(ws + 1966080);// 1,048,576
  float*          hval   = (float*)(ws + 3014656);         //   491,520
  unsigned*       pkey   = (unsigned*)(ws + 0);            // 4,194,304 (overlay, live from k_bnrelu on)
  float*          sc     = (float*)(ws + 4196352);         //     4,096
  float*          sh     = (float*)(ws + 4200448);         //     4,096
  float*          psq2   = (float*)(ws + 4204544);         //    32,768 (512x16)
  unsigned short* nfeats = (unsigned short*)(ws + 4237312);// 15,728,640
  unsigned short* w2t    = (unsigned short*)(ws + 4237312);// 4,194,304 (overlays nfeats after k_g1)
  unsigned short* x1     = (unsigned short*)(ws + 19965952);//31,457,280
  unsigned short* nbbf   = (unsigned short*)(ws + 51423232);// 2,097,152 -> end 53,520,384

  k_pg<<<BS + 512, 256, 0, stream>>>(atten, text, features, dlp_w, dlp_b,
                                     w1, w1t, nfeats, hval);
  k_dlp<<<dim3(16, NG), 256, 0, stream>>>(hval, dlp_lw, dlp_lb, nbbf, psq2);
  k_g1<<<(HH/128)*(NROWS/128), 256, 0, stream>>>(nfeats, w1t, b1, x1, psum, psq);
  k_bnw<<<4 + 2048, 256, 0, stream>>>(psum, psq, bn_g, bn_b, sc, sh, w2, w2t);
  k_bnrelu<<<(NROWS*HH/8)/256, 256, 0, stream>>>(x1, sc, sh, pkey);
  k_g2<<<(EE/256)*(NROWS/256), 512, 0, stream>>>(x1, w2t, pkey);
  k_final<<<(BS*EE/4)/256, 256, 0, stream>>>(pkey, b2, nbbf, psq2, out);
}